// Round 1
// baseline (1773.855 us; speedup 1.0000x reference)
//
#include <hip/hip_runtime.h>

#define IN_DIM 256
#define HID 128

// out[n][m] = sum_k X[n][k] * W[m][k]   (W stored row-major [M][K], i.e. X @ W^T)
// One block per row n; 128 threads, one per output column m. X row staged in LDS.
__global__ void gemm_rowwise(const float* __restrict__ X, const float* __restrict__ W,
                             float* __restrict__ out, int K) {
    __shared__ float xs[IN_DIM];
    int n = blockIdx.x;
    const float* xrow = X + (size_t)n * K;
    for (int k = threadIdx.x; k < K; k += blockDim.x) xs[k] = xrow[k];
    __syncthreads();
    int m = threadIdx.x;  // 0..127
    const float* w = W + (size_t)m * K;
    float acc = 0.f;
#pragma unroll 8
    for (int k = 0; k < K; ++k) acc += xs[k] * w[k];
    out[(size_t)n * HID + m] = acc;
}

// agg[dst[e]][j] += w[e] * fts[src[e]][j]
__global__ void spmm_scatter(const int* __restrict__ src, const int* __restrict__ dst,
                             const float* __restrict__ w, const float* __restrict__ fts,
                             float* __restrict__ agg, int E) {
    long long stride = (long long)gridDim.x * blockDim.x;
    long long total = (long long)E * HID;
    for (long long idx = (long long)blockIdx.x * blockDim.x + threadIdx.x; idx < total;
         idx += stride) {
        int e = (int)(idx >> 7);          // HID = 128
        int j = (int)(idx & (HID - 1));
        float val = w[e] * fts[(size_t)src[e] * HID + j];
        atomicAdd(&agg[(size_t)dst[e] * HID + j], val);
    }
}

// z = prelu(z + b) in place, single shared alpha
__global__ void bias_prelu(float* __restrict__ z, const float* __restrict__ b,
                           const float* __restrict__ a, int total) {
    float alpha = a[0];
    int stride = gridDim.x * blockDim.x;
    for (int idx = blockIdx.x * blockDim.x + threadIdx.x; idx < total; idx += stride) {
        float v = z[idx] + b[idx & (HID - 1)];
        z[idx] = v >= 0.f ? v : alpha * v;
    }
}

extern "C" void kernel_launch(void* const* d_in, const int* in_sizes, int n_in,
                              void* d_out, int out_size, void* d_ws, size_t ws_size,
                              hipStream_t stream) {
    const float* x  = (const float*)d_in[0];
    const int*   ei = (const int*)d_in[1];
    const float* ew = (const float*)d_in[2];
    const float* W1 = (const float*)d_in[3];
    const float* b1 = (const float*)d_in[4];
    const float* a1 = (const float*)d_in[5];
    const float* W2 = (const float*)d_in[6];
    const float* b2 = (const float*)d_in[7];
    const float* a2 = (const float*)d_in[8];
    float* out = (float*)d_out;

    int N = in_sizes[0] / IN_DIM;   // 50000
    int E = in_sizes[2];            // 800000
    const int* src = ei;
    const int* dst = ei + E;

    float* fts = (float*)d_ws;                  // N*HID floats
    float* agg = fts + (size_t)N * HID;         // N*HID floats

    size_t nbytes = (size_t)N * HID * sizeof(float);
    hipMemsetAsync(agg, 0, nbytes, stream);
    hipMemsetAsync(d_out, 0, nbytes, stream);

    // ---- layer 1 ----
    gemm_rowwise<<<N, HID, 0, stream>>>(x, W1, fts, IN_DIM);
    spmm_scatter<<<2048, 256, 0, stream>>>(src, dst, ew, fts, agg, E);
    bias_prelu<<<2048, 256, 0, stream>>>(agg, b1, a1, N * HID);

    // ---- layer 2 ----
    gemm_rowwise<<<N, HID, 0, stream>>>(agg, W2, fts, HID);
    spmm_scatter<<<2048, 256, 0, stream>>>(src, dst, ew, fts, out, E);
    bias_prelu<<<2048, 256, 0, stream>>>(out, b2, a2, N * HID);
}